// Round 8
// baseline (190.522 us; speedup 1.0000x reference)
//
#include <hip/hip_runtime.h>
#include <hip/hip_bf16.h>

// N=4, L=4096, E=1024, H=16, D=64.
// Algebra (verified passing, rounds 1-2): softmax row-sums == 1 collapse the op:
//   Z (1024x1024) = reshape(x @ Wvsum^T);  U = Z @ Wo^T + bo;  out = 16x broadcast of U.
// This round: barrier-free MFMA GEMMs with fragments loaded directly from global.

typedef unsigned short u16;
typedef __attribute__((ext_vector_type(8))) short  short8v;  // 8 bf16
typedef __attribute__((ext_vector_type(4))) float  f32x4;
typedef __attribute__((ext_vector_type(4))) u16    ushort4v;

__device__ __forceinline__ u16 f2bf(float f) {
    unsigned u = __float_as_uint(f);
    u += 0x7fffu + ((u >> 16) & 1u);
    return (u16)(u >> 16);
}
__device__ __forceinline__ float bf2f(u16 h) {
    return __uint_as_float(((unsigned)h) << 16);
}
__device__ __forceinline__ f32x4 mfma16(short8v a, short8v b, f32x4 c) {
    return __builtin_amdgcn_mfma_f32_16x16x32_bf16(a, b, c, 0, 0, 0);
}
__device__ __forceinline__ void split8(f32x4 v0, f32x4 v1, short8v& h8, short8v& l8) {
    float wf[8] = {v0[0],v0[1],v0[2],v0[3],v1[0],v1[1],v1[2],v1[3]};
#pragma unroll
    for (int j = 0; j < 8; ++j) {
        u16 hh = f2bf(wf[j]);
        h8[j] = (short)hh;
        l8[j] = (short)f2bf(wf[j] - bf2f(hh));
    }
}

// ---------------------------------------------------------------------------
// K1: pack Wvsum (fragment layout, hi/lo) and Wo (row-major bf16, hi/lo).
// ---------------------------------------------------------------------------
__global__ __launch_bounds__(256) void k_pack(const float* __restrict__ Wv,
                                              const float* __restrict__ Wo,
                                              u16* __restrict__ Bh, u16* __restrict__ Bl,
                                              u16* __restrict__ Woh, u16* __restrict__ Wol) {
    const int b = blockIdx.x;
    if (b < 512) {                       // Wo: 1M elems, 8 per thread
        const int g = b * 256 + threadIdx.x;         // 0..131071
        const f32x4* p = (const f32x4*)(Wo + (size_t)g * 8);
        short8v h8, l8; split8(p[0], p[1], h8, l8);
        ((short8v*)Woh)[g] = h8;
        ((short8v*)Wol)[g] = l8;
    } else {                             // Wvsum: 64x1024, frag-packed
        const int t  = (b - 512) * 256 + threadIdx.x;  // 0..8191
        const int c  = t >> 7;
        const int e8 = t & 127;
        f32x4 s0 = {0,0,0,0}, s1 = {0,0,0,0};
#pragma unroll
        for (int h = 0; h < 16; ++h) {
            const f32x4* p = (const f32x4*)&Wv[(size_t)((h << 6) + c) * 1024 + (e8 << 3)];
            s0 += p[0]; s1 += p[1];
        }
        short8v h8, l8; split8(s0, s1, h8, l8);
        ((short8v*)Bh)[e8 * 64 + c] = h8;
        ((short8v*)Bl)[e8 * 64 + c] = l8;
    }
}

// ---------------------------------------------------------------------------
// K2: Z = x @ Wvsum^T (reshaped).  Block = one Z row (16 x-rows) x 64 cols.
//     4 waves = 4 K-quarters; fragments loaded straight from global; one
//     LDS reduce + hi/lo split epilogue.  Grid 1024, 4 blocks/CU.
// ---------------------------------------------------------------------------
__global__ __launch_bounds__(256, 4) void k_vsum(const float* __restrict__ x,
                                                 const u16* __restrict__ Bh,
                                                 const u16* __restrict__ Bl,
                                                 u16* __restrict__ Zh,
                                                 u16* __restrict__ Zl) {
    __shared__ float red[4][64][16];     // 16 KB
    const int t = threadIdx.x, lane = t & 63, w = t >> 6;
    const int l15 = lane & 15, lh = lane >> 4;
    const int g = blockIdx.x;            // Z row
    const int R0 = g << 4;
    const int kbase = w << 8;            // 256-wide K quarter per wave
    const short8v* bh8 = (const short8v*)Bh;
    const short8v* bl8 = (const short8v*)Bl;

    f32x4 acc[4] = {{0,0,0,0},{0,0,0,0},{0,0,0,0},{0,0,0,0}};

#pragma unroll 2
    for (int kt = 0; kt < 8; ++kt) {
        const int k0 = kbase + (kt << 5);
        const float* ap = &x[(size_t)(R0 + l15) * 1024 + k0 + (lh << 3)];
        f32x4 a0 = __builtin_nontemporal_load((const f32x4*)ap);
        f32x4 a1 = __builtin_nontemporal_load((const f32x4*)(ap + 4));
        short8v ah, al; split8(a0, a1, ah, al);
        const int e8 = (k0 >> 3) + lh;
#pragma unroll
        for (int cg = 0; cg < 4; ++cg) {
            short8v bh = bh8[e8 * 64 + (cg << 4) + l15];
            short8v bl = bl8[e8 * 64 + (cg << 4) + l15];
            acc[cg] = mfma16(ah, bh, acc[cg]);
            acc[cg] = mfma16(ah, bl, acc[cg]);
            acc[cg] = mfma16(al, bh, acc[cg]);
        }
    }

#pragma unroll
    for (int cg = 0; cg < 4; ++cg)
#pragma unroll
        for (int reg = 0; reg < 4; ++reg)
            red[w][lane][(cg << 2) + reg] = acc[cg][reg];
    __syncthreads();

    ushort4v zh, zl;
#pragma unroll
    for (int j = 0; j < 4; ++j) {
        const int e = (t << 2) + j, v15 = e >> 6, c = e & 63;
        const int ln = ((v15 >> 2) << 4) | (c & 15);
        const int slot = ((c >> 4) << 2) | (v15 & 3);
        float s = red[0][ln][slot] + red[1][ln][slot] + red[2][ln][slot] + red[3][ln][slot];
        u16 hh = f2bf(s);
        zh[j] = hh;
        zl[j] = f2bf(s - bf2f(hh));
    }
    *(ushort4v*)&Zh[((size_t)g << 10) + (t << 2)] = zh;
    *(ushort4v*)&Zl[((size_t)g << 10) + (t << 2)] = zl;
}

// ---------------------------------------------------------------------------
// K3: U = Z @ Wo^T + bo, all operands pre-split bf16 (zero cvt in loop).
//     Block = 64 U-rows x 64 f-cols, 8 waves = 4 row-groups x 2 K-halves.
//     Writes U into the q=0 rows of d_out.  Grid 256 x 512 thr.
// ---------------------------------------------------------------------------
__global__ __launch_bounds__(512, 2) void k_ugemm(const u16* __restrict__ Zh,
                                                  const u16* __restrict__ Zl,
                                                  const u16* __restrict__ Woh,
                                                  const u16* __restrict__ Wol,
                                                  const float* __restrict__ bo,
                                                  float* __restrict__ out) {
    __shared__ float red[8][64][16];     // 32 KB
    const int t = threadIdx.x, lane = t & 63, w = t >> 6;
    const int l15 = lane & 15, lh = lane >> 4;
    const int rg = w & 3, kh = w >> 2;
    const int rt = blockIdx.x & 15, ct = blockIdx.x >> 4;
    const int rbase = (rt << 6) + (rg << 4), fbase = ct << 6;

    f32x4 acc[4] = {{0,0,0,0},{0,0,0,0},{0,0,0,0},{0,0,0,0}};
    const size_t arow = (size_t)(rbase + l15) << 10;

#pragma unroll 2
    for (int kt = 0; kt < 16; ++kt) {
        const int k0 = (kh << 9) + (kt << 5) + (lh << 3);
        short8v ah = *(const short8v*)&Zh[arow + k0];
        short8v al = *(const short8v*)&Zl[arow + k0];
#pragma unroll
        for (int cg = 0; cg < 4; ++cg) {
            const size_t brow = (size_t)(fbase + (cg << 4) + l15) << 10;
            short8v bh = *(const short8v*)&Woh[brow + k0];
            short8v bl = *(const short8v*)&Wol[brow + k0];
            acc[cg] = mfma16(ah, bh, acc[cg]);
            acc[cg] = mfma16(ah, bl, acc[cg]);
            acc[cg] = mfma16(al, bh, acc[cg]);
        }
    }

#pragma unroll
    for (int cg = 0; cg < 4; ++cg)
#pragma unroll
        for (int reg = 0; reg < 4; ++reg)
            red[w][lane][(cg << 2) + reg] = acc[cg][reg];
    __syncthreads();

    // 512 threads x 8 elems = 64x64 tile; bias + store to q=0 rows of out
    const int r = t >> 3, cbase = (t & 7) << 3;
    const int rg2 = r >> 4, lh2 = (r & 15) >> 2, reg2 = r & 3;
    const int ur = (rt << 6) + r;
    const int n = ur >> 8, m = ur & 255;
    float* ob = out + ((size_t)n << 22) + ((size_t)m << 10) + fbase + cbase;
#pragma unroll
    for (int jj = 0; jj < 2; ++jj) {
        f32x4 o;
#pragma unroll
        for (int q = 0; q < 4; ++q) {
            const int c = cbase + (jj << 2) + q;
            const int ln = (lh2 << 4) | (c & 15);
            const int slot = ((c >> 4) << 2) | reg2;
            o[q] = red[rg2][ln][slot] + red[4 + rg2][ln][slot] + bo[fbase + c];
        }
        *(f32x4*)(ob + (jj << 2)) = o;
    }
}

// ---------------------------------------------------------------------------
// K4: broadcast q=0 rows to q=1..15.  1024 blocks, fully coalesced 1 KB/wave
//     nontemporal stores.
// ---------------------------------------------------------------------------
__global__ __launch_bounds__(256) void k_bcast(float* __restrict__ out) {
    const int T = blockIdx.x * 256 + threadIdx.x;   // 0..262143
    const int f4 = T & 255, m = (T >> 8) & 255, n = T >> 16;
    float* src = out + ((size_t)n << 22) + ((size_t)m << 10) + (f4 << 2);
    f32x4 v = *(const f32x4*)src;
#pragma unroll
    for (int q = 1; q < 16; ++q)
        __builtin_nontemporal_store(v, (f32x4*)(src + ((size_t)q << 18)));
}

// ---------------------------------------------------------------------------
extern "C" void kernel_launch(void* const* d_in, const int* in_sizes, int n_in,
                              void* d_out, int out_size, void* d_ws, size_t ws_size,
                              hipStream_t stream) {
    const float* x  = (const float*)d_in[0];
    // d_in[1]=Wq, d_in[2]=Wk unused (softmax row-sums == 1)
    const float* Wv = (const float*)d_in[3];
    const float* Wo = (const float*)d_in[4];
    const float* bo = (const float*)d_in[5];
    float* out = (float*)d_out;

    // ws: Bh (128 KB) | Bl (128 KB)  — well under the proven 4.25 MB.
    u16* Bh = (u16*)d_ws;
    u16* Bl = Bh + 64 * 1024;

    // 8 MB of bf16 scratch carved from the tail of d_out (batch 3, rows 2048..4095):
    // written by K1/K2, consumed by K3, finally overwritten by K4's broadcast.
    // K3's q=0 writes (rows <256 of each batch) never touch it.
    u16* Woh = (u16*)(out + (size_t)14 * 1024 * 1024);   // 2 MB
    u16* Wol = Woh + 1024 * 1024;                        // 2 MB
    u16* Zh  = Wol + 1024 * 1024;                        // 2 MB
    u16* Zl  = Zh  + 1024 * 1024;                        // 2 MB

    k_pack <<<544,  256, 0, stream>>>(Wv, Wo, Bh, Bl, Woh, Wol);
    k_vsum <<<1024, 256, 0, stream>>>(x, Bh, Bl, Zh, Zl);
    k_ugemm<<<256,  512, 0, stream>>>(Zh, Zl, Woh, Wol, bo, out);
    k_bcast<<<1024, 256, 0, stream>>>(out);
}

// Round 9
// 171.321 us; speedup vs baseline: 1.1121x; 1.1121x over previous
//
#include <hip/hip_runtime.h>
#include <hip/hip_bf16.h>

// N=4, L=4096, E=1024, H=16, D=64.
// Algebra (verified passing, rounds 1/2/8): softmax row-sums == 1 collapse the op:
//   Z (1024x1024) = reshape(x @ Wvsum^T);  U = Z @ Wo^T + bo;  out = 16x broadcast of U.
// R8 evidence: k_ugemm was 40 us (1 block/CU, row-gathered B, FETCH 2.3x ideal).
// This round: fragment-packed Wo + 1024-block K-split k_ugemm. k_vsum/k_bcast unchanged.

typedef unsigned short u16;
typedef __attribute__((ext_vector_type(8))) short  short8v;  // 8 bf16
typedef __attribute__((ext_vector_type(4))) float  f32x4;
typedef __attribute__((ext_vector_type(4))) u16    ushort4v;

__device__ __forceinline__ u16 f2bf(float f) {
    unsigned u = __float_as_uint(f);
    u += 0x7fffu + ((u >> 16) & 1u);
    return (u16)(u >> 16);
}
__device__ __forceinline__ float bf2f(u16 h) {
    return __uint_as_float(((unsigned)h) << 16);
}
__device__ __forceinline__ f32x4 mfma16(short8v a, short8v b, f32x4 c) {
    return __builtin_amdgcn_mfma_f32_16x16x32_bf16(a, b, c, 0, 0, 0);
}
__device__ __forceinline__ void split8(f32x4 v0, f32x4 v1, short8v& h8, short8v& l8) {
    float wf[8] = {v0[0],v0[1],v0[2],v0[3],v1[0],v1[1],v1[2],v1[3]};
#pragma unroll
    for (int j = 0; j < 8; ++j) {
        u16 hh = f2bf(wf[j]);
        h8[j] = (short)hh;
        l8[j] = (short)f2bf(wf[j] - bf2f(hh));
    }
}

// ---------------------------------------------------------------------------
// K1: pack Wvsum (fragment layout, hi/lo) and Wo (FRAGMENT-PACKED, hi/lo):
//     Wppk8[e8*1024 + f] = short8{ Wo[f][e8*8 .. e8*8+7] }  -> coalesced B loads.
// ---------------------------------------------------------------------------
__global__ __launch_bounds__(256) void k_pack(const float* __restrict__ Wv,
                                              const float* __restrict__ Wo,
                                              u16* __restrict__ Bh, u16* __restrict__ Bl,
                                              u16* __restrict__ Wph, u16* __restrict__ Wpl) {
    const int b = blockIdx.x;
    if (b < 512) {                       // Wo: 131072 threads x 8 elems
        const int g  = b * 256 + threadIdx.x;        // 0..131071
        const int f  = g & 1023;                     // Wo row
        const int e8 = g >> 10;                      // 0..127
        const f32x4* p = (const f32x4*)(Wo + (size_t)f * 1024 + (e8 << 3));
        short8v h8, l8; split8(p[0], p[1], h8, l8);
        ((short8v*)Wph)[e8 * 1024 + f] = h8;         // consecutive g -> consecutive f: coalesced
        ((short8v*)Wpl)[e8 * 1024 + f] = l8;
    } else {                             // Wvsum: 64x1024, frag-packed
        const int t  = (b - 512) * 256 + threadIdx.x;  // 0..8191
        const int c  = t >> 7;
        const int e8 = t & 127;
        f32x4 s0 = {0,0,0,0}, s1 = {0,0,0,0};
#pragma unroll
        for (int h = 0; h < 16; ++h) {
            const f32x4* p = (const f32x4*)&Wv[(size_t)((h << 6) + c) * 1024 + (e8 << 3)];
            s0 += p[0]; s1 += p[1];
        }
        short8v h8, l8; split8(s0, s1, h8, l8);
        ((short8v*)Bh)[e8 * 64 + c] = h8;
        ((short8v*)Bl)[e8 * 64 + c] = l8;
    }
}

// ---------------------------------------------------------------------------
// K2 (unchanged from R8): Z = x @ Wvsum^T (reshaped).  Grid 1024, 4 blocks/CU.
// ---------------------------------------------------------------------------
__global__ __launch_bounds__(256, 4) void k_vsum(const float* __restrict__ x,
                                                 const u16* __restrict__ Bh,
                                                 const u16* __restrict__ Bl,
                                                 u16* __restrict__ Zh,
                                                 u16* __restrict__ Zl) {
    __shared__ float red[4][64][16];     // 16 KB
    const int t = threadIdx.x, lane = t & 63, w = t >> 6;
    const int l15 = lane & 15, lh = lane >> 4;
    const int g = blockIdx.x;            // Z row
    const int R0 = g << 4;
    const int kbase = w << 8;            // 256-wide K quarter per wave
    const short8v* bh8 = (const short8v*)Bh;
    const short8v* bl8 = (const short8v*)Bl;

    f32x4 acc[4] = {{0,0,0,0},{0,0,0,0},{0,0,0,0},{0,0,0,0}};

#pragma unroll 2
    for (int kt = 0; kt < 8; ++kt) {
        const int k0 = kbase + (kt << 5);
        const float* ap = &x[(size_t)(R0 + l15) * 1024 + k0 + (lh << 3)];
        f32x4 a0 = __builtin_nontemporal_load((const f32x4*)ap);
        f32x4 a1 = __builtin_nontemporal_load((const f32x4*)(ap + 4));
        short8v ah, al; split8(a0, a1, ah, al);
        const int e8 = (k0 >> 3) + lh;
#pragma unroll
        for (int cg = 0; cg < 4; ++cg) {
            short8v bh = bh8[e8 * 64 + (cg << 4) + l15];
            short8v bl = bl8[e8 * 64 + (cg << 4) + l15];
            acc[cg] = mfma16(ah, bh, acc[cg]);
            acc[cg] = mfma16(ah, bl, acc[cg]);
            acc[cg] = mfma16(al, bh, acc[cg]);
        }
    }

#pragma unroll
    for (int cg = 0; cg < 4; ++cg)
#pragma unroll
        for (int reg = 0; reg < 4; ++reg)
            red[w][lane][(cg << 2) + reg] = acc[cg][reg];
    __syncthreads();

    ushort4v zh, zl;
#pragma unroll
    for (int j = 0; j < 4; ++j) {
        const int e = (t << 2) + j, v15 = e >> 6, c = e & 63;
        const int ln = ((v15 >> 2) << 4) | (c & 15);
        const int slot = ((c >> 4) << 2) | (v15 & 3);
        float s = red[0][ln][slot] + red[1][ln][slot] + red[2][ln][slot] + red[3][ln][slot];
        u16 hh = f2bf(s);
        zh[j] = hh;
        zl[j] = f2bf(s - bf2f(hh));
    }
    *(ushort4v*)&Zh[((size_t)g << 10) + (t << 2)] = zh;
    *(ushort4v*)&Zl[((size_t)g << 10) + (t << 2)] = zl;
}

// ---------------------------------------------------------------------------
// K3 (rewritten): U = Z @ Wo^T + bo.  Grid 1024 = 64 rowgroups x 16 colgroups,
//     4 blocks/CU; 4 waves = K-quarters (256 each); B loads coalesced from
//     fragment-packed Wppk; padded-LDS 4-wave reduce; writes 16x64 U tile
//     into the q=0 rows of d_out.
// ---------------------------------------------------------------------------
__global__ __launch_bounds__(256, 4) void k_ugemm(const u16* __restrict__ Zh,
                                                  const u16* __restrict__ Zl,
                                                  const u16* __restrict__ Wph,
                                                  const u16* __restrict__ Wpl,
                                                  const float* __restrict__ bo,
                                                  float* __restrict__ out) {
    __shared__ float red[4][64][17];     // +1 pad: no 32-way reduce-write conflicts
    const int t = threadIdx.x, lane = t & 63, w = t >> 6;
    const int l15 = lane & 15, lh = lane >> 4;
    const int rt = blockIdx.x & 63, ct = blockIdx.x >> 6;
    const int rbase = rt << 4;           // 16 U-rows per block
    const int fbase = ct << 6;           // 64 f-cols per block
    const int kwave = w << 8;            // 256-wide K quarter per wave
    const short8v* bph = (const short8v*)Wph;
    const short8v* bpl = (const short8v*)Wpl;

    f32x4 acc[4] = {{0,0,0,0},{0,0,0,0},{0,0,0,0},{0,0,0,0}};
    const size_t arow = (size_t)(rbase + l15) << 10;

#pragma unroll 2
    for (int kt = 0; kt < 8; ++kt) {
        const int k0 = kwave + (kt << 5);
        short8v ah = *(const short8v*)&Zh[arow + k0 + (lh << 3)];
        short8v al = *(const short8v*)&Zl[arow + k0 + (lh << 3)];
        const int e8 = (k0 >> 3) + lh;
#pragma unroll
        for (int cg = 0; cg < 4; ++cg) {
            short8v bh = bph[e8 * 1024 + fbase + (cg << 4) + l15];   // coalesced
            short8v bl = bpl[e8 * 1024 + fbase + (cg << 4) + l15];
            acc[cg] = mfma16(ah, bh, acc[cg]);
            acc[cg] = mfma16(ah, bl, acc[cg]);
            acc[cg] = mfma16(al, bh, acc[cg]);
        }
    }

#pragma unroll
    for (int cg = 0; cg < 4; ++cg)
#pragma unroll
        for (int reg = 0; reg < 4; ++reg)
            red[w][lane][(cg << 2) + reg] = acc[cg][reg];
    __syncthreads();

    // 256 threads x 4 elems = 16x64 tile; 4-wave sum + bias; coalesced store
    const int i0 = t << 2;
    const int r  = i0 >> 6;              // row 0..15
    const int cb = i0 & 63;              // col base (multiple of 4)
    f32x4 o;
#pragma unroll
    for (int j = 0; j < 4; ++j) {
        const int c = cb + j;
        const int ln = ((r >> 2) << 4) | (c & 15);
        const int slot = ((c >> 4) << 2) | (r & 3);
        o[j] = red[0][ln][slot] + red[1][ln][slot] + red[2][ln][slot] + red[3][ln][slot]
             + bo[fbase + c];
    }
    const int ur = rbase + r;
    const int n = ur >> 8, m = ur & 255;
    *(f32x4*)&out[((size_t)n << 22) + ((size_t)m << 10) + fbase + cb] = o;
}

// ---------------------------------------------------------------------------
// K4 (unchanged from R8): broadcast q=0 rows to q=1..15.
// ---------------------------------------------------------------------------
__global__ __launch_bounds__(256) void k_bcast(float* __restrict__ out) {
    const int T = blockIdx.x * 256 + threadIdx.x;   // 0..262143
    const int f4 = T & 255, m = (T >> 8) & 255, n = T >> 16;
    float* src = out + ((size_t)n << 22) + ((size_t)m << 10) + (f4 << 2);
    f32x4 v = *(const f32x4*)src;
#pragma unroll
    for (int q = 1; q < 16; ++q)
        __builtin_nontemporal_store(v, (f32x4*)(src + ((size_t)q << 18)));
}

// ---------------------------------------------------------------------------
extern "C" void kernel_launch(void* const* d_in, const int* in_sizes, int n_in,
                              void* d_out, int out_size, void* d_ws, size_t ws_size,
                              hipStream_t stream) {
    const float* x  = (const float*)d_in[0];
    // d_in[1]=Wq, d_in[2]=Wk unused (softmax row-sums == 1)
    const float* Wv = (const float*)d_in[3];
    const float* Wo = (const float*)d_in[4];
    const float* bo = (const float*)d_in[5];
    float* out = (float*)d_out;

    // ws: Bh (128 KB) | Bl (128 KB)
    u16* Bh = (u16*)d_ws;
    u16* Bl = Bh + 64 * 1024;

    // 8 MB of bf16 scratch carved from the tail of d_out (batch 3, rows 2048..4095):
    // written by K1/K2, consumed by K3, finally overwritten by K4's broadcast.
    // K3's q=0 writes (rows <256 of each batch) never touch it.
    u16* Wph = (u16*)(out + (size_t)14 * 1024 * 1024);   // 2 MB (frag-packed Wo hi)
    u16* Wpl = Wph + 1024 * 1024;                        // 2 MB
    u16* Zh  = Wpl + 1024 * 1024;                        // 2 MB
    u16* Zl  = Zh  + 1024 * 1024;                        // 2 MB

    k_pack <<<544,  256, 0, stream>>>(Wv, Wo, Bh, Bl, Wph, Wpl);
    k_vsum <<<1024, 256, 0, stream>>>(x, Bh, Bl, Zh, Zl);
    k_ugemm<<<1024, 256, 0, stream>>>(Zh, Zl, Wph, Wpl, bo, out);
    k_bcast<<<1024, 256, 0, stream>>>(out);
}

// Round 11
// 170.717 us; speedup vs baseline: 1.1160x; 1.0035x over previous
//
#include <hip/hip_runtime.h>
#include <hip/hip_bf16.h>

// N=4, L=4096, E=1024, H=16, D=64.
// Algebra (verified passing, rounds 1/2/8/9): softmax row-sums == 1 collapse the op:
//   Z (1024x1024) = reshape(x @ Wvsum^T);  U = Z @ Wo^T + bo;  out = 16x broadcast of U.
// R9 evidence: ws_size = 256 MiB (poison fill) -> all scratch lives in d_ws now;
// broadcast fused into k_ugemm epilogue; k_vsum gets explicit 2-deep prefetch.

typedef unsigned short u16;
typedef __attribute__((ext_vector_type(8))) short  short8v;  // 8 bf16
typedef __attribute__((ext_vector_type(4))) float  f32x4;
typedef __attribute__((ext_vector_type(4))) u16    ushort4v;

__device__ __forceinline__ u16 f2bf(float f) {
    unsigned u = __float_as_uint(f);
    u += 0x7fffu + ((u >> 16) & 1u);
    return (u16)(u >> 16);
}
__device__ __forceinline__ float bf2f(u16 h) {
    return __uint_as_float(((unsigned)h) << 16);
}
__device__ __forceinline__ f32x4 mfma16(short8v a, short8v b, f32x4 c) {
    return __builtin_amdgcn_mfma_f32_16x16x32_bf16(a, b, c, 0, 0, 0);
}
__device__ __forceinline__ void split8(f32x4 v0, f32x4 v1, short8v& h8, short8v& l8) {
    float wf[8] = {v0[0],v0[1],v0[2],v0[3],v1[0],v1[1],v1[2],v1[3]};
#pragma unroll
    for (int j = 0; j < 8; ++j) {
        u16 hh = f2bf(wf[j]);
        h8[j] = (short)hh;
        l8[j] = (short)f2bf(wf[j] - bf2f(hh));
    }
}

// ---------------------------------------------------------------------------
// K1: pack Wvsum (fragment layout, hi/lo) and Wo (fragment-packed, hi/lo):
//     Wppk8[e8*1024 + f] = short8{ Wo[f][e8*8 .. e8*8+7] }  -> coalesced B loads.
// ---------------------------------------------------------------------------
__global__ __launch_bounds__(256) void k_pack(const float* __restrict__ Wv,
                                              const float* __restrict__ Wo,
                                              u16* __restrict__ Bh, u16* __restrict__ Bl,
                                              u16* __restrict__ Wph, u16* __restrict__ Wpl) {
    const int b = blockIdx.x;
    if (b < 512) {                       // Wo: 131072 threads x 8 elems
        const int g  = b * 256 + threadIdx.x;        // 0..131071
        const int f  = g & 1023;                     // Wo row
        const int e8 = g >> 10;                      // 0..127
        const f32x4* p = (const f32x4*)(Wo + (size_t)f * 1024 + (e8 << 3));
        short8v h8, l8; split8(p[0], p[1], h8, l8);
        ((short8v*)Wph)[e8 * 1024 + f] = h8;         // consecutive g -> consecutive f
        ((short8v*)Wpl)[e8 * 1024 + f] = l8;
    } else {                             // Wvsum: 64x1024, frag-packed
        const int t  = (b - 512) * 256 + threadIdx.x;  // 0..8191
        const int c  = t >> 7;
        const int e8 = t & 127;
        f32x4 s0 = {0,0,0,0}, s1 = {0,0,0,0};
#pragma unroll
        for (int h = 0; h < 16; ++h) {
            const f32x4* p = (const f32x4*)&Wv[(size_t)((h << 6) + c) * 1024 + (e8 << 3)];
            s0 += p[0]; s1 += p[1];
        }
        short8v h8, l8; split8(s0, s1, h8, l8);
        ((short8v*)Bh)[e8 * 64 + c] = h8;
        ((short8v*)Bl)[e8 * 64 + c] = l8;
    }
}

// ---------------------------------------------------------------------------
// K2: Z = x @ Wvsum^T (reshaped).  Grid 1024, 4 blocks/CU; explicit 2-deep
//     prefetch of the x-loads so HBM latency hides under split8+MFMA.
// ---------------------------------------------------------------------------
__global__ __launch_bounds__(256, 4) void k_vsum(const float* __restrict__ x,
                                                 const u16* __restrict__ Bh,
                                                 const u16* __restrict__ Bl,
                                                 u16* __restrict__ Zh,
                                                 u16* __restrict__ Zl) {
    __shared__ float red[4][64][16];     // 16 KB
    const int t = threadIdx.x, lane = t & 63, w = t >> 6;
    const int l15 = lane & 15, lh = lane >> 4;
    const int g = blockIdx.x;            // Z row
    const int R0 = g << 4;
    const int kbase = w << 8;            // 256-wide K quarter per wave
    const short8v* bh8 = (const short8v*)Bh;
    const short8v* bl8 = (const short8v*)Bl;

    f32x4 acc[4] = {{0,0,0,0},{0,0,0,0},{0,0,0,0},{0,0,0,0}};

    const float* ap = &x[(size_t)(R0 + l15) * 1024 + kbase + (lh << 3)];
    f32x4 a0 = __builtin_nontemporal_load((const f32x4*)ap);
    f32x4 a1 = __builtin_nontemporal_load((const f32x4*)(ap + 4));

#pragma unroll
    for (int kt = 0; kt < 8; ++kt) {
        f32x4 n0 = a0, n1 = a1;
        if (kt < 7) {                    // prefetch next k-tile before consuming current
            const float* apn = ap + ((kt + 1) << 5);
            n0 = __builtin_nontemporal_load((const f32x4*)apn);
            n1 = __builtin_nontemporal_load((const f32x4*)(apn + 4));
        }
        short8v ah, al; split8(a0, a1, ah, al);
        const int e8 = ((kbase + (kt << 5)) >> 3) + lh;
#pragma unroll
        for (int cg = 0; cg < 4; ++cg) {
            short8v bh = bh8[e8 * 64 + (cg << 4) + l15];
            short8v bl = bl8[e8 * 64 + (cg << 4) + l15];
            acc[cg] = mfma16(ah, bh, acc[cg]);
            acc[cg] = mfma16(ah, bl, acc[cg]);
            acc[cg] = mfma16(al, bh, acc[cg]);
        }
        a0 = n0; a1 = n1;
    }

#pragma unroll
    for (int cg = 0; cg < 4; ++cg)
#pragma unroll
        for (int reg = 0; reg < 4; ++reg)
            red[w][lane][(cg << 2) + reg] = acc[cg][reg];
    __syncthreads();

    ushort4v zh, zl;
#pragma unroll
    for (int j = 0; j < 4; ++j) {
        const int e = (t << 2) + j, v15 = e >> 6, c = e & 63;
        const int ln = ((v15 >> 2) << 4) | (c & 15);
        const int slot = ((c >> 4) << 2) | (v15 & 3);
        float s = red[0][ln][slot] + red[1][ln][slot] + red[2][ln][slot] + red[3][ln][slot];
        u16 hh = f2bf(s);
        zh[j] = hh;
        zl[j] = f2bf(s - bf2f(hh));
    }
    *(ushort4v*)&Zh[((size_t)g << 10) + (t << 2)] = zh;
    *(ushort4v*)&Zl[((size_t)g << 10) + (t << 2)] = zl;
}

// ---------------------------------------------------------------------------
// K3: U = Z @ Wo^T + bo with FUSED 16x broadcast epilogue (k_bcast eliminated).
//     Grid 1024 = 64 rowgroups x 16 colgroups, 4 blocks/CU; 4 waves = K-quarters;
//     coalesced B from fragment-packed Wppk; padded-LDS reduce; each thread
//     stores its f32x4 to all 16 q-slots (256B segments, 1MB stride).
// ---------------------------------------------------------------------------
__global__ __launch_bounds__(256, 4) void k_ugemm(const u16* __restrict__ Zh,
                                                  const u16* __restrict__ Zl,
                                                  const u16* __restrict__ Wph,
                                                  const u16* __restrict__ Wpl,
                                                  const float* __restrict__ bo,
                                                  float* __restrict__ out) {
    __shared__ float red[4][64][17];     // +1 pad: conflict-free reduce
    const int t = threadIdx.x, lane = t & 63, w = t >> 6;
    const int l15 = lane & 15, lh = lane >> 4;
    const int rt = blockIdx.x & 63, ct = blockIdx.x >> 6;
    const int rbase = rt << 4;           // 16 U-rows per block
    const int fbase = ct << 6;           // 64 f-cols per block
    const int kwave = w << 8;            // 256-wide K quarter per wave
    const short8v* bph = (const short8v*)Wph;
    const short8v* bpl = (const short8v*)Wpl;

    f32x4 acc[4] = {{0,0,0,0},{0,0,0,0},{0,0,0,0},{0,0,0,0}};
    const size_t arow = (size_t)(rbase + l15) << 10;

#pragma unroll 2
    for (int kt = 0; kt < 8; ++kt) {
        const int k0 = kwave + (kt << 5);
        short8v ah = *(const short8v*)&Zh[arow + k0 + (lh << 3)];
        short8v al = *(const short8v*)&Zl[arow + k0 + (lh << 3)];
        const int e8 = (k0 >> 3) + lh;
#pragma unroll
        for (int cg = 0; cg < 4; ++cg) {
            short8v bh = bph[e8 * 1024 + fbase + (cg << 4) + l15];   // coalesced
            short8v bl = bpl[e8 * 1024 + fbase + (cg << 4) + l15];
            acc[cg] = mfma16(ah, bh, acc[cg]);
            acc[cg] = mfma16(ah, bl, acc[cg]);
            acc[cg] = mfma16(al, bh, acc[cg]);
        }
    }

#pragma unroll
    for (int cg = 0; cg < 4; ++cg)
#pragma unroll
        for (int reg = 0; reg < 4; ++reg)
            red[w][lane][(cg << 2) + reg] = acc[cg][reg];
    __syncthreads();

    // 256 threads x 4 elems = 16x64 U tile; 4-wave sum + bias; 16x broadcast store
    const int i0 = t << 2;
    const int r  = i0 >> 6;              // row 0..15
    const int cb = i0 & 63;              // col base (multiple of 4)
    f32x4 o;
#pragma unroll
    for (int j = 0; j < 4; ++j) {
        const int c = cb + j;
        const int ln = ((r >> 2) << 4) | (c & 15);
        const int slot = ((c >> 4) << 2) | (r & 3);
        o[j] = red[0][ln][slot] + red[1][ln][slot] + red[2][ln][slot] + red[3][ln][slot]
             + bo[fbase + c];
    }
    const int ur = rbase + r;
    const int n = ur >> 8, m = ur & 255;
    float* ob = out + ((size_t)n << 22) + ((size_t)m << 10) + fbase + cb;
#pragma unroll
    for (int q = 0; q < 16; ++q)
        __builtin_nontemporal_store(o, (f32x4*)(ob + ((size_t)q << 18)));
}

// ---------------------------------------------------------------------------
extern "C" void kernel_launch(void* const* d_in, const int* in_sizes, int n_in,
                              void* d_out, int out_size, void* d_ws, size_t ws_size,
                              hipStream_t stream) {
    const float* x  = (const float*)d_in[0];
    // d_in[1]=Wq, d_in[2]=Wk unused (softmax row-sums == 1)
    const float* Wv = (const float*)d_in[3];
    const float* Wo = (const float*)d_in[4];
    const float* bo = (const float*)d_in[5];
    float* out = (float*)d_out;

    // All scratch in d_ws (ws_size = 256 MiB per R9 poison-fill evidence):
    // Bh(128K) | Bl(128K) | Wph(2M) | Wpl(2M) | Zh(2M) | Zl(2M) = 8.25 MB.
    u16* Bh  = (u16*)d_ws;
    u16* Bl  = Bh  + 64 * 1024;
    u16* Wph = Bl  + 64 * 1024;
    u16* Wpl = Wph + 1024 * 1024;
    u16* Zh  = Wpl + 1024 * 1024;
    u16* Zl  = Zh  + 1024 * 1024;

    k_pack <<<544,  256, 0, stream>>>(Wv, Wo, Bh, Bl, Wph, Wpl);
    k_vsum <<<1024, 256, 0, stream>>>(x, Bh, Bl, Zh, Zl);
    k_ugemm<<<1024, 256, 0, stream>>>(Zh, Zl, Wph, Wpl, bo, out);
}